// Round 14
// baseline (254.473 us; speedup 1.0000x reference)
//
#include <hip/hip_runtime.h>

#define NPHI 64
#define NS 8
#define NK 16
#define BATCH 512

typedef __attribute__((__ext_vector_type__(2))) float v2f;

// v_pk_fma_f32 acc = p * b + acc, with op_sel/neg variants (validated on HW in R10).
#define PK_BL(acc, p, b)  asm("v_pk_fma_f32 %0, %1, %2, %0 op_sel:[0,0,0] op_sel_hi:[1,0,1]" : "+v"(acc) : "v"(p), "v"(b))   // acc += p * {b.x,b.x}
#define PK_BH(acc, p, b)  asm("v_pk_fma_f32 %0, %1, %2, %0 op_sel:[0,1,0] op_sel_hi:[1,1,1]" : "+v"(acc) : "v"(p), "v"(b))   // acc += p * {b.y,b.y}
#define PK_BLN(acc, p, b) asm("v_pk_fma_f32 %0, %1, %2, %0 op_sel:[0,0,0] op_sel_hi:[1,0,1] neg_lo:[0,1,0] neg_hi:[0,1,0]" : "+v"(acc) : "v"(p), "v"(b)) // acc += p * {-b.x,-b.x}
#define PK_X(acc, p, b)   asm("v_pk_fma_f32 %0, %1, %2, %0 op_sel:[1,1,0] op_sel_hi:[0,1,1] neg_lo:[1,0,0]" : "+v"(acc) : "v"(p), "v"(b))   // acc += {-p.y, p.x} * b.y
#define PK_XH(acc, p, b)  asm("v_pk_fma_f32 %0, %1, %2, %0 op_sel:[1,1,0] op_sel_hi:[0,1,1] neg_hi:[1,0,0]" : "+v"(acc) : "v"(p), "v"(b))   // acc += {p.y, -p.x} * b.y
#define PK_XLO(acc, p, b) asm("v_pk_fma_f32 %0, %1, %2, %0 op_sel:[1,0,0] op_sel_hi:[0,0,1] neg_hi:[1,0,0]" : "+v"(acc) : "v"(p), "v"(b))   // acc += {p.y, -p.x} * b.x

// In-place Gauss-Jordan (sweep-operator) inversion of an 8x8 complex matrix
// held one element per lane (lane = i*8+j). No pivoting: HPD input.
__device__ __forceinline__ void cinv8(float& ar, float& ai, int lane) {
    const int i = lane >> 3, j = lane & 7;
#pragma unroll
    for (int p = 0; p < 8; ++p) {
        const float pr = __shfl(ar, p * 9, 64);
        const float pi = __shfl(ai, p * 9, 64);
        const float den = pr * pr + pi * pi;
        const float rr = pr / den, ri = -pi / den;           // r = 1/pivot
        const float aipr = __shfl(ar, (i << 3) | p, 64);
        const float aipi = __shfl(ai, (i << 3) | p, 64);
        const float apjr = __shfl(ar, (p << 3) | j, 64);
        const float apji = __shfl(ai, (p << 3) | j, 64);
        const float br = rr * apjr - ri * apji;              // r*a[p][j]
        const float bi = rr * apji + ri * apjr;
        const float er = ar - (aipr * br - aipi * bi);       // eliminate
        const float ei = ai - (aipr * bi + aipi * br);
        const float rowr = rr * ar - ri * ai;                // pivot row/col
        const float rowi = rr * ai + ri * ar;
        const bool ip = (i == p), jp = (j == p);
        const float nr = ip ? (jp ? rr : rowr) : (jp ? -rowr : er);
        const float ni = ip ? (jp ? ri : rowi) : (jp ? -rowi : ei);
        ar = nr; ai = ni;
    }
}

// ONE WAVE per (k,b); 4 independent waves per block; no __syncthreads.
// R13 structure, ONE change: launch_bounds min-waves/EU 2 -> 6 to test
// whether "amdgpu-waves-per-eu"="2" was capping residency at ~2 blocks/CU
// (occupancy pinned at 30% across R8-R13 despite VGPR/LDS headroom).
__global__ __launch_bounds__(256, 6) void k_grad_diag(
    const float* __restrict__ PhiR, const float* __restrict__ PhiI,
    const float* __restrict__ GhR, const float* __restrict__ GhI,
    const float* __restrict__ LamR, const float* __restrict__ LamI,
    const float* __restrict__ CR, const float* __restrict__ CI,
    const float* __restrict__ Beta,
    float* __restrict__ out, int region)
{
    const int tid = threadIdx.x;
    const int w = tid >> 6;          // wave id in block
    const int lane = tid & 63;
    const int gw = blockIdx.x * 4 + w;
    const int k = gw & (NK - 1);     // 4 waves of a block share b -> share Phi in L1
    const int b = gw >> 4;
    const int kb = k * BATCH + b;

    __shared__ __align__(16) float2 sM[4][NPHI][10];  // M^T: sM[w][f][s] = M[s,f]  20KB
    __shared__ float2 sQ2[4][64];                     // Qi^2, lane=(s*8+t)          2KB

    const float* phiR = PhiR + b * 4096;
    const float* phiI = PhiI + b * 4096;
    const float* ghR = GhR + kb * 512;
    const float* ghI = GhI + kb * 512;
    const float invb = 1.0f / Beta[kb];

    // M accumulators (kept live through S)
    v2f accr[4], acci[4];
    // T accumulators (kept live through S and d)
    v2f acc2[8];

    // ---- M[s,f] = sum_e conj(gh[e,s]) * phi[e,f] ; lane = f (depth-4 pipeline)
    {
#pragma unroll
        for (int sp = 0; sp < 4; ++sp) { accr[sp] = (v2f)0.f; acci[sp] = (v2f)0.f; }
        float pA[4], qA[4], pB[4], qB[4];
#pragma unroll
        for (int u = 0; u < 4; ++u) {
            pA[u] = phiR[u * 64 + lane];
            qA[u] = phiI[u * 64 + lane];
        }
#pragma unroll 1
        for (int eb = 0; eb < 64; eb += 8) {
#pragma unroll
            for (int u = 0; u < 4; ++u) {          // prefetch half B
                pB[u] = phiR[(eb + 4 + u) * 64 + lane];
                qB[u] = phiI[(eb + 4 + u) * 64 + lane];
            }
#pragma unroll
            for (int u = 0; u < 4; ++u) {          // compute half A
                const int e = eb + u;
                const v2f* g2 = (const v2f*)(ghR + e * 8);
                const v2f* h2 = (const v2f*)(ghI + e * 8);
                v2f pp; pp.x = pA[u]; pp.y = qA[u];
#pragma unroll
                for (int sp = 0; sp < 4; ++sp) {
                    const v2f g = g2[sp];
                    const v2f h = h2[sp];
                    PK_BL(accr[sp], g, pp);        // mr += gr*pr
                    PK_BH(accr[sp], h, pp);        // mr += gi*pi
                    PK_BH(acci[sp], g, pp);        // mi += gr*pi
                    PK_BLN(acci[sp], h, pp);       // mi -= gi*pr
                }
            }
            if (eb + 8 < 64) {
#pragma unroll
                for (int u = 0; u < 4; ++u) {      // prefetch next half A
                    pA[u] = phiR[(eb + 8 + u) * 64 + lane];
                    qA[u] = phiI[(eb + 8 + u) * 64 + lane];
                }
            }
#pragma unroll
            for (int u = 0; u < 4; ++u) {          // compute half B
                const int e = eb + 4 + u;
                const v2f* g2 = (const v2f*)(ghR + e * 8);
                const v2f* h2 = (const v2f*)(ghI + e * 8);
                v2f pp; pp.x = pB[u]; pp.y = qB[u];
#pragma unroll
                for (int sp = 0; sp < 4; ++sp) {
                    const v2f g = g2[sp];
                    const v2f h = h2[sp];
                    PK_BL(accr[sp], g, pp);
                    PK_BH(accr[sp], h, pp);
                    PK_BH(acci[sp], g, pp);
                    PK_BLN(acci[sp], h, pp);
                }
            }
        }
#pragma unroll
        for (int sp = 0; sp < 4; ++sp) {
            sM[w][lane][2 * sp]     = make_float2(accr[sp].x, acci[sp].x);
            sM[w][lane][2 * sp + 1] = make_float2(accr[sp].y, acci[sp].y);
        }
    }

    // ---- T[s,g] = sum_f M[s,f]*C[f,g] ; lane = g. DEPTH-8 pipeline on the
    // C stream (the HBM-latency-critical one): 16 loads in flight per wave.
    {
        const float* cR = CR + (size_t)kb * 4096;
        const float* cI = CI + (size_t)kb * 4096;
#pragma unroll
        for (int s = 0; s < 8; ++s) acc2[s] = (v2f)0.f;
        float pA[8], qA[8], pB[8], qB[8];
#pragma unroll
        for (int u = 0; u < 8; ++u) {
            pA[u] = cR[u * 64 + lane];
            qA[u] = cI[u * 64 + lane];
        }
#pragma unroll 1
        for (int fb = 0; fb < 64; fb += 16) {
#pragma unroll
            for (int u = 0; u < 8; ++u) {          // prefetch block B
                pB[u] = cR[(fb + 8 + u) * 64 + lane];
                qB[u] = cI[(fb + 8 + u) * 64 + lane];
            }
#pragma unroll
            for (int u = 0; u < 8; ++u) {          // compute block A
                const int f = fb + u;
                const v2f* mrow = (const v2f*)(&sM[w][f][0]);  // broadcast reads
                v2f cc; cc.x = pA[u]; cc.y = qA[u];
#pragma unroll
                for (int s = 0; s < 8; ++s) {
                    const v2f ms = mrow[s];
                    PK_BL(acc2[s], cc, ms);        // += Mr*{cr,ci}
                    PK_X(acc2[s], cc, ms);         // += Mi*{-ci,cr}
                }
            }
            if (fb + 16 < 64) {
#pragma unroll
                for (int u = 0; u < 8; ++u) {      // prefetch next block A
                    pA[u] = cR[(fb + 16 + u) * 64 + lane];
                    qA[u] = cI[(fb + 16 + u) * 64 + lane];
                }
            }
#pragma unroll
            for (int u = 0; u < 8; ++u) {          // compute block B
                const int f = fb + 8 + u;
                const v2f* mrow = (const v2f*)(&sM[w][f][0]);
                v2f cc; cc.x = pB[u]; cc.y = qB[u];
#pragma unroll
                for (int s = 0; s < 8; ++s) {
                    const v2f ms = mrow[s];
                    PK_BL(acc2[s], cc, ms);
                    PK_X(acc2[s], cc, ms);
                }
            }
        }
    }

    // Lam loads hoisted: latency hides under the S butterfly
    const float lamr = LamR[kb * 64 + lane];
    const float lami = LamI[kb * 64 + lane];

    // ---- S[s,t] = (sum_g T[s,g]*conj(M[t,g])) / beta via register butterfly.
    float sre, sim;
    {
        const bool l0 = (lane & 1) != 0;
        const bool l1 = (lane & 2) != 0;
        const bool l2 = (lane & 4) != 0;
        v2f Sv = (v2f)0.f;
#pragma unroll
        for (int s = 0; s < 8; ++s) {
            v2f p[8];
#pragma unroll
            for (int t = 0; t < 8; ++t) {
                v2f acc = (v2f)0.f;
                const v2f mre = accr[t >> 1];
                const v2f mim = acci[t >> 1];
                if (t & 1) { PK_BH(acc, acc2[s], mre); PK_XH(acc, acc2[s], mim); }
                else       { PK_BL(acc, acc2[s], mre); PK_XLO(acc, acc2[s], mim); }
                p[t] = acc;
            }
            v2f q[4];
#pragma unroll
            for (int j = 0; j < 4; ++j) {
                v2f snd = l0 ? p[2 * j] : p[2 * j + 1];
                v2f kp  = l0 ? p[2 * j + 1] : p[2 * j];
                kp.x += __shfl_xor(snd.x, 1, 64);
                kp.y += __shfl_xor(snd.y, 1, 64);
                q[j] = kp;
            }
            v2f r[2];
#pragma unroll
            for (int m = 0; m < 2; ++m) {
                v2f snd = l1 ? q[2 * m] : q[2 * m + 1];
                v2f kp  = l1 ? q[2 * m + 1] : q[2 * m];
                kp.x += __shfl_xor(snd.x, 2, 64);
                kp.y += __shfl_xor(snd.y, 2, 64);
                r[m] = kp;
            }
            v2f snd = l2 ? r[0] : r[1];
            v2f v   = l2 ? r[1] : r[0];
            v.x += __shfl_xor(snd.x, 4, 64);
            v.y += __shfl_xor(snd.y, 4, 64);
            v.x += __shfl_xor(v.x, 8, 64);  v.y += __shfl_xor(v.y, 8, 64);
            v.x += __shfl_xor(v.x, 16, 64); v.y += __shfl_xor(v.y, 16, 64);
            v.x += __shfl_xor(v.x, 32, 64); v.y += __shfl_xor(v.y, 32, 64);
            Sv = ((lane >> 3) == s) ? v : Sv;
        }
        sre = Sv.x * invb; sim = Sv.y * invb;
    }

    // ---- Q = inv(Lam) + S ; Qi = inv(Q); Qi2 = Qi@Qi   (lane = i*8+j)
    {
        float ar = lamr, ai = lami;
        cinv8(ar, ai, lane);
        ar += sre; ai += sim;
        cinv8(ar, ai, lane);
        const int i = lane >> 3, j = lane & 7;
        float qr = 0.f, qi = 0.f;
#pragma unroll
        for (int t = 0; t < 8; ++t) {
            const float xr = __shfl(ar, (i << 3) | t, 64);
            const float xi = __shfl(ai, (i << 3) | t, 64);
            const float yr = __shfl(ar, (t << 3) | j, 64);
            const float yi = __shfl(ai, (t << 3) | j, 64);
            qr += xr * yr - xi * yi;
            qi += xr * yi + xi * yr;
        }
        sQ2[w][lane] = make_float2(qr, qi);
    }

    // ---- d[f] = (sum_s gh[f,s] * sum_t Qi2[s,t]*T[t,f]) / beta ; lane = f
    {
        const float4 a0 = *(const float4*)(ghR + lane * 8);   // L1-hot
        const float4 a1 = *(const float4*)(ghR + lane * 8 + 4);
        const float4 c0 = *(const float4*)(ghI + lane * 8);
        const float4 c1 = *(const float4*)(ghI + lane * 8 + 4);
        const float gfr[8] = {a0.x, a0.y, a0.z, a0.w, a1.x, a1.y, a1.z, a1.w};
        const float gfi[8] = {c0.x, c0.y, c0.z, c0.w, c1.x, c1.y, c1.z, c1.w};
        float dre = 0.f, dim = 0.f;
#pragma unroll
        for (int s = 0; s < 8; ++s) {
            float yr = 0.f, yi = 0.f;
#pragma unroll
            for (int t = 0; t < 8; ++t) {
                const float2 q = sQ2[w][s * 8 + t];   // broadcast
                yr += q.x * acc2[t].x - q.y * acc2[t].y;
                yi += q.x * acc2[t].y + q.y * acc2[t].x;
            }
            dre += gfr[s] * yr - gfi[s] * yi;
            dim += gfr[s] * yi + gfi[s] * yr;
        }
        float2* scr = (float2*)(out + (size_t)b * region + k * 128);
        scr[lane] = make_float2(dre * invb, dim * invb);
    }
}

// One block per b: step-size NN, diagonal Riemannian update, clamp, store.
// Reads own-region scratch (front 2048 floats) before overwriting the region.
__global__ __launch_bounds__(256) void k_finalize(
    const float* __restrict__ PhiR, const float* __restrict__ PhiI,
    const float* __restrict__ bnG, const float* __restrict__ bnB,
    const float* __restrict__ bnM, const float* __restrict__ bnV,
    const float* __restrict__ W, const float* __restrict__ Bb,
    float* __restrict__ out, int region, int cplx)
{
    const int b = blockIdx.x;
    const int tid = threadIdx.x;
    __shared__ float sIQ[128];
    __shared__ float sRed[2];
    __shared__ float sDre[64], sDim[64];

    const float* phiR = PhiR + b * 4096;
    const float* phiI = PhiI + b * 4096;
    float* outp = out + (size_t)b * region;

    // diagonal eg sum over k from own-region scratch (read BEFORE any writes)
    float er = 0.f, ei = 0.f;
    if (tid < 64) {
        const int f = tid;
#pragma unroll
        for (int kk = 0; kk < NK; ++kk) {
            const float2 dv = ((const float2*)(outp + kk * 128))[f];
            er += dv.x; ei += dv.y;
        }
    }

    // row sums of Phi (Phi @ ones): 4 threads per row
    {
        const int r = tid >> 2, pq = tid & 3;
        float sr = 0.f, si = 0.f;
        const float4* a4 = (const float4*)(phiR + r * 64 + pq * 16);
        const float4* c4 = (const float4*)(phiI + r * 64 + pq * 16);
#pragma unroll
        for (int q = 0; q < 4; ++q) {
            const float4 a = a4[q]; sr += (a.x + a.y) + (a.z + a.w);
            const float4 c = c4[q]; si += (c.x + c.y) + (c.z + c.w);
        }
        sr += __shfl_xor(sr, 1, 64); si += __shfl_xor(si, 1, 64);
        sr += __shfl_xor(sr, 2, 64); si += __shfl_xor(si, 2, 64);
        if (pq == 0) { sIQ[r] = sr; sIQ[64 + r] = si; }
    }
    __syncthreads();

    // BN -> Dense(1) -> leaky_relu
    if (tid < 128) {
        const float v = sIQ[tid];
        const float t = bnG[tid] * (v - bnM[tid]) * rsqrtf(bnV[tid] + 1e-3f) + bnB[tid];
        float contrib = t * W[tid];
#pragma unroll
        for (int o = 1; o < 64; o <<= 1) contrib += __shfl_xor(contrib, o, 64);
        if ((tid & 63) == 0) sRed[tid >> 6] = contrib;
    }
    __syncthreads();
    const float s_lin = sRed[0] + sRed[1] + Bb[0];
    const float step = (s_lin >= 0.f) ? s_lin : 0.1f * s_lin;

    // diagonal Riemannian gradient + norm (rg is exactly 0 off-diagonal)
    if (tid < 64) {
        const int f = tid;
        er *= -(1.0f / NK); ei *= -(1.0f / NK);
        const float prr = phiR[f * 65];
        const float pii = phiI[f * 65];
        const float proj = er * prr + ei * pii;     // Re(eg * conj(Phi))
        const float rr = er - proj * prr;
        const float ri = ei - proj * pii;
        float n2 = rr * rr + ri * ri;
#pragma unroll
        for (int o = 1; o < 64; o <<= 1) n2 += __shfl_xor(n2, o, 64);
        const float sc = step / sqrtf(n2);
        sDre[f] = sc * rr;
        sDim[f] = sc * ri;
    }
    __syncthreads();   // all scratch reads done; safe to overwrite region

    // elementwise: subtract diag update, magnitude clamp, store
#pragma unroll
    for (int p = 0; p < 4; ++p) {
        const int base = p * 1024 + tid * 4;
        const float4 a = *(const float4*)(phiR + base);
        const float4 c = *(const float4*)(phiI + base);
        const int row = base >> 6;
        const int col0 = base & 63;
        float re[4] = {a.x, a.y, a.z, a.w};
        float im[4] = {c.x, c.y, c.z, c.w};
#pragma unroll
        for (int q = 0; q < 4; ++q) {
            if (row == col0 + q) { re[q] -= sDre[row]; im[q] -= sDim[row]; }
            const float ab = sqrtf(re[q] * re[q] + im[q] * im[q]);
            const float den = fmaxf(ab - 1.f, 0.f) + 1.f;
            re[q] /= den; im[q] /= den;
        }
        if (cplx) {
            *(float4*)(outp + base * 2)     = make_float4(re[0], im[0], re[1], im[1]);
            *(float4*)(outp + base * 2 + 4) = make_float4(re[2], im[2], re[3], im[3]);
        } else {
            *(float4*)(outp + base) = make_float4(re[0], re[1], re[2], re[3]);
        }
    }
}

extern "C" void kernel_launch(void* const* d_in, const int* in_sizes, int n_in,
                              void* d_out, int out_size, void* d_ws, size_t ws_size,
                              hipStream_t stream) {
    const float* PhiR = (const float*)d_in[0];
    const float* PhiI = (const float*)d_in[1];
    const float* GhR  = (const float*)d_in[2];
    const float* GhI  = (const float*)d_in[3];
    const float* LamR = (const float*)d_in[4];
    const float* LamI = (const float*)d_in[5];
    const float* CR   = (const float*)d_in[6];
    const float* CI   = (const float*)d_in[7];
    const float* Beta = (const float*)d_in[8];
    const float* bnG  = (const float*)d_in[9];
    const float* bnB  = (const float*)d_in[10];
    const float* bnM  = (const float*)d_in[11];
    const float* bnV  = (const float*)d_in[12];
    const float* W    = (const float*)d_in[13];
    const float* Bb   = (const float*)d_in[14];
    float* outp = (float*)d_out;

    // out_size == B*64*64  -> real-part-only float32 layout
    // out_size == B*64*64*2 -> interleaved complex64 layout
    const int cplx = (out_size >= 3000000) ? 1 : 0;
    const int region = cplx ? 8192 : 4096;

    k_grad_diag<<<(NK * BATCH) / 4, 256, 0, stream>>>(PhiR, PhiI, GhR, GhI,
                                                      LamR, LamI, CR, CI, Beta,
                                                      outp, region);
    k_finalize<<<BATCH, 256, 0, stream>>>(PhiR, PhiI,
                                          bnG, bnB, bnM, bnV, W, Bb,
                                          outp, region, cplx);
}

// Round 15
// 133.969 us; speedup vs baseline: 1.8995x; 1.8995x over previous
//
#include <hip/hip_runtime.h>

#define NPHI 64
#define NS 8
#define NK 16
#define BATCH 512

typedef __attribute__((__ext_vector_type__(2))) float v2f;

// v_pk_fma_f32 acc = p * b + acc, with op_sel/neg variants (validated on HW in R10).
#define PK_BL(acc, p, b)  asm("v_pk_fma_f32 %0, %1, %2, %0 op_sel:[0,0,0] op_sel_hi:[1,0,1]" : "+v"(acc) : "v"(p), "v"(b))   // acc += p * {b.x,b.x}
#define PK_BH(acc, p, b)  asm("v_pk_fma_f32 %0, %1, %2, %0 op_sel:[0,1,0] op_sel_hi:[1,1,1]" : "+v"(acc) : "v"(p), "v"(b))   // acc += p * {b.y,b.y}
#define PK_BLN(acc, p, b) asm("v_pk_fma_f32 %0, %1, %2, %0 op_sel:[0,0,0] op_sel_hi:[1,0,1] neg_lo:[0,1,0] neg_hi:[0,1,0]" : "+v"(acc) : "v"(p), "v"(b)) // acc += p * {-b.x,-b.x}
#define PK_X(acc, p, b)   asm("v_pk_fma_f32 %0, %1, %2, %0 op_sel:[1,1,0] op_sel_hi:[0,1,1] neg_lo:[1,0,0]" : "+v"(acc) : "v"(p), "v"(b))   // acc += {-p.y, p.x} * b.y
#define PK_XH(acc, p, b)  asm("v_pk_fma_f32 %0, %1, %2, %0 op_sel:[1,1,0] op_sel_hi:[0,1,1] neg_hi:[1,0,0]" : "+v"(acc) : "v"(p), "v"(b))   // acc += {p.y, -p.x} * b.y
#define PK_XLO(acc, p, b) asm("v_pk_fma_f32 %0, %1, %2, %0 op_sel:[1,0,0] op_sel_hi:[0,0,1] neg_hi:[1,0,0]" : "+v"(acc) : "v"(p), "v"(b))   // acc += {p.y, -p.x} * b.x

// In-place Gauss-Jordan (sweep-operator) inversion of an 8x8 complex matrix
// held one element per lane (lane = i*8+j). No pivoting: HPD input.
__device__ __forceinline__ void cinv8(float& ar, float& ai, int lane) {
    const int i = lane >> 3, j = lane & 7;
#pragma unroll
    for (int p = 0; p < 8; ++p) {
        const float pr = __shfl(ar, p * 9, 64);
        const float pi = __shfl(ai, p * 9, 64);
        const float den = pr * pr + pi * pi;
        const float rr = pr / den, ri = -pi / den;           // r = 1/pivot
        const float aipr = __shfl(ar, (i << 3) | p, 64);
        const float aipi = __shfl(ai, (i << 3) | p, 64);
        const float apjr = __shfl(ar, (p << 3) | j, 64);
        const float apji = __shfl(ai, (p << 3) | j, 64);
        const float br = rr * apjr - ri * apji;              // r*a[p][j]
        const float bi = rr * apji + ri * apjr;
        const float er = ar - (aipr * br - aipi * bi);       // eliminate
        const float ei = ai - (aipr * bi + aipi * br);
        const float rowr = rr * ar - ri * ai;                // pivot row/col
        const float rowi = rr * ai + ri * ar;
        const bool ip = (i == p), jp = (j == p);
        const float nr = ip ? (jp ? rr : rowr) : (jp ? -rowr : er);
        const float ni = ip ? (jp ? ri : rowi) : (jp ? -rowi : ei);
        ar = nr; ai = ni;
    }
}

// ONE WAVE per (k,b); 4 independent waves per block; no __syncthreads.
// Final configuration (R13, best measured 133.9us): depth-4 pipeline on the
// L2-hot Phi stream, depth-8 pipeline on the HBM-critical C stream, packed
// v_pk_fma_f32 complex MACs, register-butterfly S, shuffle Gauss-Jordan.
// launch_bounds(256,2): VGPR cap 256; natural pressure 64, no spill.
__global__ __launch_bounds__(256, 2) void k_grad_diag(
    const float* __restrict__ PhiR, const float* __restrict__ PhiI,
    const float* __restrict__ GhR, const float* __restrict__ GhI,
    const float* __restrict__ LamR, const float* __restrict__ LamI,
    const float* __restrict__ CR, const float* __restrict__ CI,
    const float* __restrict__ Beta,
    float* __restrict__ out, int region)
{
    const int tid = threadIdx.x;
    const int w = tid >> 6;          // wave id in block
    const int lane = tid & 63;
    const int gw = blockIdx.x * 4 + w;
    const int k = gw & (NK - 1);     // 4 waves of a block share b -> share Phi in L1
    const int b = gw >> 4;
    const int kb = k * BATCH + b;

    __shared__ __align__(16) float2 sM[4][NPHI][10];  // M^T: sM[w][f][s] = M[s,f]  20KB
    __shared__ float2 sQ2[4][64];                     // Qi^2, lane=(s*8+t)          2KB

    const float* phiR = PhiR + b * 4096;
    const float* phiI = PhiI + b * 4096;
    const float* ghR = GhR + kb * 512;
    const float* ghI = GhI + kb * 512;
    const float invb = 1.0f / Beta[kb];

    // M accumulators (kept live through S)
    v2f accr[4], acci[4];
    // T accumulators (kept live through S and d)
    v2f acc2[8];

    // ---- M[s,f] = sum_e conj(gh[e,s]) * phi[e,f] ; lane = f (depth-4 pipeline)
    {
#pragma unroll
        for (int sp = 0; sp < 4; ++sp) { accr[sp] = (v2f)0.f; acci[sp] = (v2f)0.f; }
        float pA[4], qA[4], pB[4], qB[4];
#pragma unroll
        for (int u = 0; u < 4; ++u) {
            pA[u] = phiR[u * 64 + lane];
            qA[u] = phiI[u * 64 + lane];
        }
#pragma unroll 1
        for (int eb = 0; eb < 64; eb += 8) {
#pragma unroll
            for (int u = 0; u < 4; ++u) {          // prefetch half B
                pB[u] = phiR[(eb + 4 + u) * 64 + lane];
                qB[u] = phiI[(eb + 4 + u) * 64 + lane];
            }
#pragma unroll
            for (int u = 0; u < 4; ++u) {          // compute half A
                const int e = eb + u;
                const v2f* g2 = (const v2f*)(ghR + e * 8);
                const v2f* h2 = (const v2f*)(ghI + e * 8);
                v2f pp; pp.x = pA[u]; pp.y = qA[u];
#pragma unroll
                for (int sp = 0; sp < 4; ++sp) {
                    const v2f g = g2[sp];
                    const v2f h = h2[sp];
                    PK_BL(accr[sp], g, pp);        // mr += gr*pr
                    PK_BH(accr[sp], h, pp);        // mr += gi*pi
                    PK_BH(acci[sp], g, pp);        // mi += gr*pi
                    PK_BLN(acci[sp], h, pp);       // mi -= gi*pr
                }
            }
            if (eb + 8 < 64) {
#pragma unroll
                for (int u = 0; u < 4; ++u) {      // prefetch next half A
                    pA[u] = phiR[(eb + 8 + u) * 64 + lane];
                    qA[u] = phiI[(eb + 8 + u) * 64 + lane];
                }
            }
#pragma unroll
            for (int u = 0; u < 4; ++u) {          // compute half B
                const int e = eb + 4 + u;
                const v2f* g2 = (const v2f*)(ghR + e * 8);
                const v2f* h2 = (const v2f*)(ghI + e * 8);
                v2f pp; pp.x = pB[u]; pp.y = qB[u];
#pragma unroll
                for (int sp = 0; sp < 4; ++sp) {
                    const v2f g = g2[sp];
                    const v2f h = h2[sp];
                    PK_BL(accr[sp], g, pp);
                    PK_BH(accr[sp], h, pp);
                    PK_BH(acci[sp], g, pp);
                    PK_BLN(acci[sp], h, pp);
                }
            }
        }
#pragma unroll
        for (int sp = 0; sp < 4; ++sp) {
            sM[w][lane][2 * sp]     = make_float2(accr[sp].x, acci[sp].x);
            sM[w][lane][2 * sp + 1] = make_float2(accr[sp].y, acci[sp].y);
        }
    }

    // ---- T[s,g] = sum_f M[s,f]*C[f,g] ; lane = g. DEPTH-8 pipeline on the
    // C stream (the HBM-latency-critical one): 16 loads in flight per wave.
    {
        const float* cR = CR + (size_t)kb * 4096;
        const float* cI = CI + (size_t)kb * 4096;
#pragma unroll
        for (int s = 0; s < 8; ++s) acc2[s] = (v2f)0.f;
        float pA[8], qA[8], pB[8], qB[8];
#pragma unroll
        for (int u = 0; u < 8; ++u) {
            pA[u] = cR[u * 64 + lane];
            qA[u] = cI[u * 64 + lane];
        }
#pragma unroll 1
        for (int fb = 0; fb < 64; fb += 16) {
#pragma unroll
            for (int u = 0; u < 8; ++u) {          // prefetch block B
                pB[u] = cR[(fb + 8 + u) * 64 + lane];
                qB[u] = cI[(fb + 8 + u) * 64 + lane];
            }
#pragma unroll
            for (int u = 0; u < 8; ++u) {          // compute block A
                const int f = fb + u;
                const v2f* mrow = (const v2f*)(&sM[w][f][0]);  // broadcast reads
                v2f cc; cc.x = pA[u]; cc.y = qA[u];
#pragma unroll
                for (int s = 0; s < 8; ++s) {
                    const v2f ms = mrow[s];
                    PK_BL(acc2[s], cc, ms);        // += Mr*{cr,ci}
                    PK_X(acc2[s], cc, ms);         // += Mi*{-ci,cr}
                }
            }
            if (fb + 16 < 64) {
#pragma unroll
                for (int u = 0; u < 8; ++u) {      // prefetch next block A
                    pA[u] = cR[(fb + 16 + u) * 64 + lane];
                    qA[u] = cI[(fb + 16 + u) * 64 + lane];
                }
            }
#pragma unroll
            for (int u = 0; u < 8; ++u) {          // compute block B
                const int f = fb + 8 + u;
                const v2f* mrow = (const v2f*)(&sM[w][f][0]);
                v2f cc; cc.x = pB[u]; cc.y = qB[u];
#pragma unroll
                for (int s = 0; s < 8; ++s) {
                    const v2f ms = mrow[s];
                    PK_BL(acc2[s], cc, ms);
                    PK_X(acc2[s], cc, ms);
                }
            }
        }
    }

    // Lam loads hoisted: latency hides under the S butterfly
    const float lamr = LamR[kb * 64 + lane];
    const float lami = LamI[kb * 64 + lane];

    // ---- S[s,t] = (sum_g T[s,g]*conj(M[t,g])) / beta via register butterfly.
    float sre, sim;
    {
        const bool l0 = (lane & 1) != 0;
        const bool l1 = (lane & 2) != 0;
        const bool l2 = (lane & 4) != 0;
        v2f Sv = (v2f)0.f;
#pragma unroll
        for (int s = 0; s < 8; ++s) {
            v2f p[8];
#pragma unroll
            for (int t = 0; t < 8; ++t) {
                v2f acc = (v2f)0.f;
                const v2f mre = accr[t >> 1];
                const v2f mim = acci[t >> 1];
                if (t & 1) { PK_BH(acc, acc2[s], mre); PK_XH(acc, acc2[s], mim); }
                else       { PK_BL(acc, acc2[s], mre); PK_XLO(acc, acc2[s], mim); }
                p[t] = acc;
            }
            v2f q[4];
#pragma unroll
            for (int j = 0; j < 4; ++j) {
                v2f snd = l0 ? p[2 * j] : p[2 * j + 1];
                v2f kp  = l0 ? p[2 * j + 1] : p[2 * j];
                kp.x += __shfl_xor(snd.x, 1, 64);
                kp.y += __shfl_xor(snd.y, 1, 64);
                q[j] = kp;
            }
            v2f r[2];
#pragma unroll
            for (int m = 0; m < 2; ++m) {
                v2f snd = l1 ? q[2 * m] : q[2 * m + 1];
                v2f kp  = l1 ? q[2 * m + 1] : q[2 * m];
                kp.x += __shfl_xor(snd.x, 2, 64);
                kp.y += __shfl_xor(snd.y, 2, 64);
                r[m] = kp;
            }
            v2f snd = l2 ? r[0] : r[1];
            v2f v   = l2 ? r[1] : r[0];
            v.x += __shfl_xor(snd.x, 4, 64);
            v.y += __shfl_xor(snd.y, 4, 64);
            v.x += __shfl_xor(v.x, 8, 64);  v.y += __shfl_xor(v.y, 8, 64);
            v.x += __shfl_xor(v.x, 16, 64); v.y += __shfl_xor(v.y, 16, 64);
            v.x += __shfl_xor(v.x, 32, 64); v.y += __shfl_xor(v.y, 32, 64);
            Sv = ((lane >> 3) == s) ? v : Sv;
        }
        sre = Sv.x * invb; sim = Sv.y * invb;
    }

    // ---- Q = inv(Lam) + S ; Qi = inv(Q); Qi2 = Qi@Qi   (lane = i*8+j)
    {
        float ar = lamr, ai = lami;
        cinv8(ar, ai, lane);
        ar += sre; ai += sim;
        cinv8(ar, ai, lane);
        const int i = lane >> 3, j = lane & 7;
        float qr = 0.f, qi = 0.f;
#pragma unroll
        for (int t = 0; t < 8; ++t) {
            const float xr = __shfl(ar, (i << 3) | t, 64);
            const float xi = __shfl(ai, (i << 3) | t, 64);
            const float yr = __shfl(ar, (t << 3) | j, 64);
            const float yi = __shfl(ai, (t << 3) | j, 64);
            qr += xr * yr - xi * yi;
            qi += xr * yi + xi * yr;
        }
        sQ2[w][lane] = make_float2(qr, qi);
    }

    // ---- d[f] = (sum_s gh[f,s] * sum_t Qi2[s,t]*T[t,f]) / beta ; lane = f
    {
        const float4 a0 = *(const float4*)(ghR + lane * 8);   // L1-hot
        const float4 a1 = *(const float4*)(ghR + lane * 8 + 4);
        const float4 c0 = *(const float4*)(ghI + lane * 8);
        const float4 c1 = *(const float4*)(ghI + lane * 8 + 4);
        const float gfr[8] = {a0.x, a0.y, a0.z, a0.w, a1.x, a1.y, a1.z, a1.w};
        const float gfi[8] = {c0.x, c0.y, c0.z, c0.w, c1.x, c1.y, c1.z, c1.w};
        float dre = 0.f, dim = 0.f;
#pragma unroll
        for (int s = 0; s < 8; ++s) {
            float yr = 0.f, yi = 0.f;
#pragma unroll
            for (int t = 0; t < 8; ++t) {
                const float2 q = sQ2[w][s * 8 + t];   // broadcast
                yr += q.x * acc2[t].x - q.y * acc2[t].y;
                yi += q.x * acc2[t].y + q.y * acc2[t].x;
            }
            dre += gfr[s] * yr - gfi[s] * yi;
            dim += gfr[s] * yi + gfi[s] * yr;
        }
        float2* scr = (float2*)(out + (size_t)b * region + k * 128);
        scr[lane] = make_float2(dre * invb, dim * invb);
    }
}

// One block per b: step-size NN, diagonal Riemannian update, clamp, store.
// Reads own-region scratch (front 2048 floats) before overwriting the region.
__global__ __launch_bounds__(256) void k_finalize(
    const float* __restrict__ PhiR, const float* __restrict__ PhiI,
    const float* __restrict__ bnG, const float* __restrict__ bnB,
    const float* __restrict__ bnM, const float* __restrict__ bnV,
    const float* __restrict__ W, const float* __restrict__ Bb,
    float* __restrict__ out, int region, int cplx)
{
    const int b = blockIdx.x;
    const int tid = threadIdx.x;
    __shared__ float sIQ[128];
    __shared__ float sRed[2];
    __shared__ float sDre[64], sDim[64];

    const float* phiR = PhiR + b * 4096;
    const float* phiI = PhiI + b * 4096;
    float* outp = out + (size_t)b * region;

    // diagonal eg sum over k from own-region scratch (read BEFORE any writes)
    float er = 0.f, ei = 0.f;
    if (tid < 64) {
        const int f = tid;
#pragma unroll
        for (int kk = 0; kk < NK; ++kk) {
            const float2 dv = ((const float2*)(outp + kk * 128))[f];
            er += dv.x; ei += dv.y;
        }
    }

    // row sums of Phi (Phi @ ones): 4 threads per row
    {
        const int r = tid >> 2, pq = tid & 3;
        float sr = 0.f, si = 0.f;
        const float4* a4 = (const float4*)(phiR + r * 64 + pq * 16);
        const float4* c4 = (const float4*)(phiI + r * 64 + pq * 16);
#pragma unroll
        for (int q = 0; q < 4; ++q) {
            const float4 a = a4[q]; sr += (a.x + a.y) + (a.z + a.w);
            const float4 c = c4[q]; si += (c.x + c.y) + (c.z + c.w);
        }
        sr += __shfl_xor(sr, 1, 64); si += __shfl_xor(si, 1, 64);
        sr += __shfl_xor(sr, 2, 64); si += __shfl_xor(si, 2, 64);
        if (pq == 0) { sIQ[r] = sr; sIQ[64 + r] = si; }
    }
    __syncthreads();

    // BN -> Dense(1) -> leaky_relu
    if (tid < 128) {
        const float v = sIQ[tid];
        const float t = bnG[tid] * (v - bnM[tid]) * rsqrtf(bnV[tid] + 1e-3f) + bnB[tid];
        float contrib = t * W[tid];
#pragma unroll
        for (int o = 1; o < 64; o <<= 1) contrib += __shfl_xor(contrib, o, 64);
        if ((tid & 63) == 0) sRed[tid >> 6] = contrib;
    }
    __syncthreads();
    const float s_lin = sRed[0] + sRed[1] + Bb[0];
    const float step = (s_lin >= 0.f) ? s_lin : 0.1f * s_lin;

    // diagonal Riemannian gradient + norm (rg is exactly 0 off-diagonal)
    if (tid < 64) {
        const int f = tid;
        er *= -(1.0f / NK); ei *= -(1.0f / NK);
        const float prr = phiR[f * 65];
        const float pii = phiI[f * 65];
        const float proj = er * prr + ei * pii;     // Re(eg * conj(Phi))
        const float rr = er - proj * prr;
        const float ri = ei - proj * pii;
        float n2 = rr * rr + ri * ri;
#pragma unroll
        for (int o = 1; o < 64; o <<= 1) n2 += __shfl_xor(n2, o, 64);
        const float sc = step / sqrtf(n2);
        sDre[f] = sc * rr;
        sDim[f] = sc * ri;
    }
    __syncthreads();   // all scratch reads done; safe to overwrite region

    // elementwise: subtract diag update, magnitude clamp, store
#pragma unroll
    for (int p = 0; p < 4; ++p) {
        const int base = p * 1024 + tid * 4;
        const float4 a = *(const float4*)(phiR + base);
        const float4 c = *(const float4*)(phiI + base);
        const int row = base >> 6;
        const int col0 = base & 63;
        float re[4] = {a.x, a.y, a.z, a.w};
        float im[4] = {c.x, c.y, c.z, c.w};
#pragma unroll
        for (int q = 0; q < 4; ++q) {
            if (row == col0 + q) { re[q] -= sDre[row]; im[q] -= sDim[row]; }
            const float ab = sqrtf(re[q] * re[q] + im[q] * im[q]);
            const float den = fmaxf(ab - 1.f, 0.f) + 1.f;
            re[q] /= den; im[q] /= den;
        }
        if (cplx) {
            *(float4*)(outp + base * 2)     = make_float4(re[0], im[0], re[1], im[1]);
            *(float4*)(outp + base * 2 + 4) = make_float4(re[2], im[2], re[3], im[3]);
        } else {
            *(float4*)(outp + base) = make_float4(re[0], re[1], re[2], re[3]);
        }
    }
}

extern "C" void kernel_launch(void* const* d_in, const int* in_sizes, int n_in,
                              void* d_out, int out_size, void* d_ws, size_t ws_size,
                              hipStream_t stream) {
    const float* PhiR = (const float*)d_in[0];
    const float* PhiI = (const float*)d_in[1];
    const float* GhR  = (const float*)d_in[2];
    const float* GhI  = (const float*)d_in[3];
    const float* LamR = (const float*)d_in[4];
    const float* LamI = (const float*)d_in[5];
    const float* CR   = (const float*)d_in[6];
    const float* CI   = (const float*)d_in[7];
    const float* Beta = (const float*)d_in[8];
    const float* bnG  = (const float*)d_in[9];
    const float* bnB  = (const float*)d_in[10];
    const float* bnM  = (const float*)d_in[11];
    const float* bnV  = (const float*)d_in[12];
    const float* W    = (const float*)d_in[13];
    const float* Bb   = (const float*)d_in[14];
    float* outp = (float*)d_out;

    // out_size == B*64*64  -> real-part-only float32 layout
    // out_size == B*64*64*2 -> interleaved complex64 layout
    const int cplx = (out_size >= 3000000) ? 1 : 0;
    const int region = cplx ? 8192 : 4096;

    k_grad_diag<<<(NK * BATCH) / 4, 256, 0, stream>>>(PhiR, PhiI, GhR, GhI,
                                                      LamR, LamI, CR, CI, Beta,
                                                      outp, region);
    k_finalize<<<BATCH, 256, 0, stream>>>(PhiR, PhiI,
                                          bnG, bnB, bnM, bnV, W, Bb,
                                          outp, region, cplx);
}